// Round 10
// baseline (688.641 us; speedup 1.0000x reference)
//
#include <hip/hip_runtime.h>
#include <math.h>

#define NB 64
#define NS 2048
#define NH 512
#define NE 512
#define NV 50257
#define H3 1536
#define KSL 8          // k1 split-K slices
#define NCH 32         // k3 s-chunks per b

// ---- DIAGNOSTIC amplification factors (surface kernels above the ~150us
// harness poison-fill floor in the rocprof top-5). Deterministic: each rep
// recomputes identical values; k6 stores only on the final rep. ----
#define K1REP 24
#define K3REP 6
#define K6REP 6

typedef __attribute__((ext_vector_type(8))) short bf16x8;
typedef __attribute__((ext_vector_type(4))) float f32x4;

// ---- workspace layout (float offsets) ----
#define GI_OFF    0                            // [8][1536][64] gi split-K partials
#define GH_OFF    (GI_OFF + KSL*H3*NB)         // [8][1536][64]
#define HNEW_OFF  (GH_OFF + KSL*H3*NB)         // [64][512]
#define EN_OFF    (HNEW_OFF + NB*NH)           // [64][2048] raw energies
#define PCTX_OFF  (EN_OFF + NB*NS)             // [64][32][512] partial ctx
#define PM_OFF    (PCTX_OFF + NB*NCH*NH)       // [64][32] partial max
#define PL_OFF    (PM_OFF + NB*NCH)            // [64][32] partial sum
#define CPART_OFF (PL_OFF + NB*NCH)            // [4][512][64] concat partials
#define CTX_OFF   (CPART_OFF + 4*NH*NB)        // [64][512]
#define CCB_OFF   (CTX_OFF + NB*NH)            // [64][512] concat_output bf16 (ushort)

// ---- d_out layout (float offsets) ----
#define HID_OFF  ((size_t)NB*NV)
#define ATTN_OFF (HID_OFF + (size_t)NB*NH)

__device__ __forceinline__ unsigned short f2bf(float f) {
    unsigned u = __builtin_bit_cast(unsigned, f);
    u += 0x7FFFu + ((u >> 16) & 1u);   // RNE
    return (unsigned short)(u >> 16);
}

// K1: split-K(8) GRU input GEMMs. grid (96 j-tiles, 8 k-slices). AMPLIFIED x24.
__global__ __launch_bounds__(256) void k1_gru_gemm(
    const int* __restrict__ seq, const float* __restrict__ lh,
    const float* __restrict__ emb, const float* __restrict__ wih,
    const float* __restrict__ whh, float* __restrict__ ws)
{
    __shared__ float xl[64][65];
    __shared__ float hl[64][65];
    __shared__ int idxl[64];
    const int t = threadIdx.x;
    const int b = t & 63;
    const int j0 = __builtin_amdgcn_readfirstlane(blockIdx.x * 16 + (t >> 6) * 4);
    const int k0 = blockIdx.y * 64;
    if (t < 64) idxl[t] = seq[t];
    __syncthreads();
    {   // stage x/h [64][64]: 4 threads per row, 16B chunks
        const int r = t >> 2;
        const int c = (t & 3) * 16;
        #pragma unroll
        for (int q = 0; q < 4; ++q) {
            const float4 xv = *(const float4*)&emb[(size_t)idxl[r] * NE + k0 + c + q*4];
            const float4 hv = *(const float4*)&lh[r * NH + k0 + c + q*4];
            xl[r][c+q*4+0]=xv.x; xl[r][c+q*4+1]=xv.y; xl[r][c+q*4+2]=xv.z; xl[r][c+q*4+3]=xv.w;
            hl[r][c+q*4+0]=hv.x; hl[r][c+q*4+1]=hv.y; hl[r][c+q*4+2]=hv.z; hl[r][c+q*4+3]=hv.w;
        }
    }
    __syncthreads();
    #pragma unroll 1
    for (int rep = 0; rep < K1REP; ++rep) {
        asm volatile("" ::: "memory");   // force reload each rep (no cross-rep CSE)
        float ai[4] = {0.f,0.f,0.f,0.f};
        float ah[4] = {0.f,0.f,0.f,0.f};
        #pragma unroll 4
        for (int e = 0; e < 64; e += 4) {
            const float x0=xl[b][e], x1=xl[b][e+1], x2=xl[b][e+2], x3=xl[b][e+3];
            const float h0=hl[b][e], h1=hl[b][e+1], h2=hl[b][e+2], h3=hl[b][e+3];
            #pragma unroll
            for (int jj = 0; jj < 4; ++jj) {
                const float4 wi = *(const float4*)&wih[(size_t)(j0+jj)*NE + k0 + e];
                const float4 wh = *(const float4*)&whh[(size_t)(j0+jj)*NH + k0 + e];
                ai[jj] = fmaf(x0,wi.x, fmaf(x1,wi.y, fmaf(x2,wi.z, fmaf(x3,wi.w, ai[jj]))));
                ah[jj] = fmaf(h0,wh.x, fmaf(h1,wh.y, fmaf(h2,wh.z, fmaf(h3,wh.w, ah[jj]))));
            }
        }
        float* gi = ws + GI_OFF + (size_t)blockIdx.y * H3 * NB;
        float* gh = ws + GH_OFF + (size_t)blockIdx.y * H3 * NB;
        #pragma unroll
        for (int jj = 0; jj < 4; ++jj) {
            gi[(j0+jj)*NB + b] = ai[jj];
            gh[(j0+jj)*NB + b] = ah[jj];
        }
    }
}

// K2: combine 8 split-K partials + biases, GRU gate math -> h_new
__global__ __launch_bounds__(256) void k2_gates(
    const float* __restrict__ lh, const float* __restrict__ bih,
    const float* __restrict__ bhh, float* __restrict__ ws, float* __restrict__ out)
{
    const int gid = blockIdx.x * 256 + threadIdx.x;
    const int b = gid & 63;
    const int h = gid >> 6;
    const float* gi = ws + GI_OFF;
    const float* gh = ws + GH_OFF;
    const int P = H3 * NB;
    float ir = bih[h], iz = bih[512+h], inn = bih[1024+h];
    float hr = bhh[h], hz = bhh[512+h], hnn = bhh[1024+h];
    #pragma unroll
    for (int s = 0; s < KSL; ++s) {
        ir  += gi[s*P + h*NB + b];
        iz  += gi[s*P + (512+h)*NB + b];
        inn += gi[s*P + (1024+h)*NB + b];
        hr  += gh[s*P + h*NB + b];
        hz  += gh[s*P + (512+h)*NB + b];
        hnn += gh[s*P + (1024+h)*NB + b];
    }
    const float r = 1.f / (1.f + __expf(-(ir + hr)));
    const float z = 1.f / (1.f + __expf(-(iz + hz)));
    const float nx = inn + r * hnn;
    const float e2 = __expf(-2.f * fabsf(nx));
    const float n = copysignf((1.f - e2) / (1.f + e2), nx);
    const float hnew = (1.f - z) * n + z * lh[b*NH + h];
    ws[HNEW_OFF + b*NH + h] = hnew;
    out[HID_OFF + (size_t)b*NH + h] = hnew;
}

// K3: flash-style attention pass. grid 2048 = b(64) x chunk(32). AMPLIFIED x6.
__global__ __launch_bounds__(256) void k3_attn(
    const float* __restrict__ enc, float* __restrict__ ws)
{
    const int t = threadIdx.x;
    const int w = t >> 6;
    const int l = t & 63;
    const int b = blockIdx.x >> 5;
    const int chunk = blockIdx.x & 31;
    const float* hn = ws + HNEW_OFF + b * NH;
    const float4 hq0 = *(const float4*)&hn[l*4];
    const float4 hq1 = *(const float4*)&hn[256 + l*4];
    const int s0 = chunk * 64 + w * 16;
    const float* rowb = enc + ((size_t)s0 * NB + b) * NH;
    __shared__ float ctxl[4][NH];
    __shared__ float ml[4], ll[4];
    #pragma unroll 1
    for (int rep = 0; rep < K3REP; ++rep) {
        asm volatile("" ::: "memory");
        float m = -INFINITY, lsum = 0.f;
        float cx[8] = {0.f,0.f,0.f,0.f,0.f,0.f,0.f,0.f};
        float ekeep = 0.f;
        f32x4 a0 = __builtin_nontemporal_load((const f32x4*)&rowb[l*4]);
        f32x4 a1 = __builtin_nontemporal_load((const f32x4*)&rowb[256 + l*4]);
        for (int i = 0; i < 16; ++i) {
            const f32x4 r0 = a0, r1 = a1;
            if (i < 15) {
                const float* nr = rowb + (size_t)(i+1) * NB * NH;
                a0 = __builtin_nontemporal_load((const f32x4*)&nr[l*4]);
                a1 = __builtin_nontemporal_load((const f32x4*)&nr[256 + l*4]);
            }
            float d = r0.x*hq0.x;
            d = fmaf(r0.y,hq0.y,d); d = fmaf(r0.z,hq0.z,d); d = fmaf(r0.w,hq0.w,d);
            d = fmaf(r1.x,hq1.x,d); d = fmaf(r1.y,hq1.y,d); d = fmaf(r1.z,hq1.z,d); d = fmaf(r1.w,hq1.w,d);
            d += __shfl_xor(d, 32);
            d += __shfl_xor(d, 16);
            d += __shfl_xor(d, 8);
            d += __shfl_xor(d, 4);
            d += __shfl_xor(d, 2);
            d += __shfl_xor(d, 1);
            if (l == i) ekeep = d;
            const float mn = fmaxf(m, d);
            if (mn > m) {   // wave-uniform (d uniform after full reduce)
                const float sc = __expf(m - mn);
                lsum *= sc;
                #pragma unroll
                for (int k = 0; k < 8; ++k) cx[k] *= sc;
                m = mn;
            }
            const float p = __expf(d - m);
            lsum += p;
            cx[0]=fmaf(p,r0.x,cx[0]); cx[1]=fmaf(p,r0.y,cx[1]);
            cx[2]=fmaf(p,r0.z,cx[2]); cx[3]=fmaf(p,r0.w,cx[3]);
            cx[4]=fmaf(p,r1.x,cx[4]); cx[5]=fmaf(p,r1.y,cx[5]);
            cx[6]=fmaf(p,r1.z,cx[6]); cx[7]=fmaf(p,r1.w,cx[7]);
        }
        if (l < 16) ws[EN_OFF + (size_t)b * NS + s0 + l] = ekeep;
        #pragma unroll
        for (int k = 0; k < 4; ++k) {
            ctxl[w][l*4+k]       = cx[k];
            ctxl[w][256 + l*4+k] = cx[4+k];
        }
        if (l == 0) { ml[w] = m; ll[w] = lsum; }
        __syncthreads();
        const float M = fmaxf(fmaxf(ml[0], ml[1]), fmaxf(ml[2], ml[3]));
        const float w0 = __expf(ml[0]-M), w1 = __expf(ml[1]-M);
        const float w2 = __expf(ml[2]-M), w3 = __expf(ml[3]-M);
        for (int e = t; e < NH; e += 256) {
            const float c = ctxl[0][e]*w0 + ctxl[1][e]*w1 + ctxl[2][e]*w2 + ctxl[3][e]*w3;
            ws[PCTX_OFF + ((size_t)b*NCH + chunk)*NH + e] = c;
        }
        if (t == 0) {
            ws[PM_OFF + b*NCH + chunk] = M;
            ws[PL_OFF + b*NCH + chunk] = ll[0]*w0 + ll[1]*w1 + ll[2]*w2 + ll[3]*w3;
        }
        __syncthreads();   // protect shared state before next rep rewrites
    }
}

// K4: combine the 32 partials per b -> ctx (normalized) + attn output.
__global__ __launch_bounds__(256) void k4_combine(
    float* __restrict__ ws, float* __restrict__ out)
{
    const int b = blockIdx.x;
    const int sl = blockIdx.y;
    const int t = threadIdx.x;
    __shared__ float pml[NCH], pll[NCH], pwl[NCH];
    if (t < NCH) { pml[t] = ws[PM_OFF + b*NCH + t]; pll[t] = ws[PL_OFF + b*NCH + t]; }
    __syncthreads();
    float M = -INFINITY;
    #pragma unroll
    for (int c = 0; c < NCH; ++c) M = fmaxf(M, pml[c]);
    if (t < NCH) pwl[t] = __expf(pml[t] - M);
    __syncthreads();
    float L = 0.f;
    #pragma unroll
    for (int c = 0; c < NCH; ++c) L += pll[c] * pwl[c];
    const float invL = 1.f / L;
    const int e = sl * 128 + (t & 127);
    if (t < 128) {
        float acc = 0.f;
        #pragma unroll 8
        for (int c = 0; c < NCH; ++c)
            acc += ws[PCTX_OFF + ((size_t)b*NCH + c)*NH + e] * pwl[c];
        ws[CTX_OFF + b*NH + e] = acc * invL;
    }
    for (int s = sl * 512 + t; s < sl * 512 + 512; s += 256)
        out[ATTN_OFF + (size_t)b*NS + s] = __expf(ws[EN_OFF + (size_t)b*NS + s] - M) * invL;
}

// K5: concat GEMM partials: [64,1024] @ w_concat.T, split-K over 4 chunks of 256
__global__ __launch_bounds__(256) void k5_concat_gemm(
    const float* __restrict__ wcat, float* __restrict__ ws)
{
    __shared__ float al[64][65];
    const int t = threadIdx.x;
    const int b = t & 63;
    const int j0 = __builtin_amdgcn_readfirstlane(blockIdx.x * 16 + (t >> 6) * 4);
    const int kc = blockIdx.y;
    const float* A = ws + ((kc < 2) ? HNEW_OFF : CTX_OFF);
    const int kb = (kc & 1) * 256;
    float acc[4] = {0.f,0.f,0.f,0.f};
    const int c4 = (t & 15) * 4;
    const int r0 = t >> 4;
    for (int ch = 0; ch < 4; ++ch) {
        const int k0 = kb + ch * 64;
        __syncthreads();
        #pragma unroll
        for (int i = 0; i < 4; ++i) {
            const int r = r0 + i * 16;
            const float4 v = *(const float4*)&A[r * NH + k0 + c4];
            al[r][c4+0]=v.x; al[r][c4+1]=v.y; al[r][c4+2]=v.z; al[r][c4+3]=v.w;
        }
        __syncthreads();
        #pragma unroll 4
        for (int e = 0; e < 64; e += 4) {
            const float a0v=al[b][e], a1v=al[b][e+1], a2v=al[b][e+2], a3v=al[b][e+3];
            #pragma unroll
            for (int jj = 0; jj < 4; ++jj) {
                const float4 wq = *(const float4*)&wcat[(size_t)(j0+jj)*1024 + kc*256 + ch*64 + e];
                acc[jj] = fmaf(a0v,wq.x, fmaf(a1v,wq.y, fmaf(a2v,wq.z, fmaf(a3v,wq.w, acc[jj]))));
            }
        }
    }
    #pragma unroll
    for (int jj = 0; jj < 4; ++jj)
        ws[CPART_OFF + ((size_t)kc*NH + j0+jj)*NB + b] = acc[jj];
}

// K5b: sum split-K partials + bias + tanh -> concat_output (bf16 for MFMA k6)
__global__ __launch_bounds__(256) void k5b_concat_fin(
    const float* __restrict__ bcat, float* __restrict__ ws)
{
    const int t = threadIdx.x;
    const int b = t & 63;
    const int j = blockIdx.x * 4 + (t >> 6);
    float v = bcat[j];
    #pragma unroll
    for (int kc = 0; kc < 4; ++kc)
        v += ws[CPART_OFF + ((size_t)kc*NH + j)*NB + b];
    const float e2 = __expf(-2.f * fabsf(v));
    const float th = copysignf((1.f - e2) / (1.f + e2), v);
    unsigned short* ccb = (unsigned short*)(ws + CCB_OFF);
    ccb[b*NH + j] = f2bf(th);
}

// K6: vocab projection via bf16 MFMA (plain R4-style body). AMPLIFIED x6,
// stores only on the last rep.
__global__ __launch_bounds__(128) void k6_mfma(
    const float* __restrict__ wout, const float* __restrict__ bout,
    const unsigned short* __restrict__ ccb, float* __restrict__ out)
{
    const int t = threadIdx.x;
    const int w = t >> 6;
    const int l = t & 63;
    const int lm = l & 15;
    const int kg = l >> 4;
    const int j = blockIdx.x * 32 + w * 16 + lm;
    const int jc = j < NV ? j : NV - 1;
    const float* wrow = wout + (size_t)jc * NH + kg * 8;
    #pragma unroll 1
    for (int rep = 0; rep < K6REP; ++rep) {
        asm volatile("" ::: "memory");
        f32x4 acc0 = {0.f,0.f,0.f,0.f};
        f32x4 acc1 = {0.f,0.f,0.f,0.f};
        f32x4 acc2 = {0.f,0.f,0.f,0.f};
        f32x4 acc3 = {0.f,0.f,0.f,0.f};
        #pragma unroll 4
        for (int ks = 0; ks < 16; ++ks) {
            const float4 w0 = *(const float4*)(wrow + ks * 32);
            const float4 w1 = *(const float4*)(wrow + ks * 32 + 4);
            bf16x8 bf;
            bf[0] = (short)f2bf(w0.x); bf[1] = (short)f2bf(w0.y);
            bf[2] = (short)f2bf(w0.z); bf[3] = (short)f2bf(w0.w);
            bf[4] = (short)f2bf(w1.x); bf[5] = (short)f2bf(w1.y);
            bf[6] = (short)f2bf(w1.z); bf[7] = (short)f2bf(w1.w);
            const int ka = ks * 32 + kg * 8;
            const bf16x8 a0 = *(const bf16x8*)&ccb[(0*16 + lm) * NH + ka];
            const bf16x8 a1 = *(const bf16x8*)&ccb[(1*16 + lm) * NH + ka];
            const bf16x8 a2 = *(const bf16x8*)&ccb[(2*16 + lm) * NH + ka];
            const bf16x8 a3 = *(const bf16x8*)&ccb[(3*16 + lm) * NH + ka];
            acc0 = __builtin_amdgcn_mfma_f32_16x16x32_bf16(a0, bf, acc0, 0, 0, 0);
            acc1 = __builtin_amdgcn_mfma_f32_16x16x32_bf16(a1, bf, acc1, 0, 0, 0);
            acc2 = __builtin_amdgcn_mfma_f32_16x16x32_bf16(a2, bf, acc2, 0, 0, 0);
            acc3 = __builtin_amdgcn_mfma_f32_16x16x32_bf16(a3, bf, acc3, 0, 0, 0);
        }
        if (rep == K6REP - 1 && j < NV) {
            const float bj = bout[jc];
            #pragma unroll
            for (int r = 0; r < 4; ++r) {
                out[(size_t)(0*16 + kg*4 + r) * NV + j] = acc0[r] + bj;
                out[(size_t)(1*16 + kg*4 + r) * NV + j] = acc1[r] + bj;
                out[(size_t)(2*16 + kg*4 + r) * NV + j] = acc2[r] + bj;
                out[(size_t)(3*16 + kg*4 + r) * NV + j] = acc3[r] + bj;
            }
        }
    }
}

extern "C" void kernel_launch(void* const* d_in, const int* in_sizes, int n_in,
                              void* d_out, int out_size, void* d_ws, size_t ws_size,
                              hipStream_t stream) {
    (void)in_sizes; (void)n_in; (void)out_size; (void)ws_size;
    const int*   seq  = (const int*)  d_in[0];
    const float* lh   = (const float*)d_in[1];
    const float* enc  = (const float*)d_in[2];
    const float* emb  = (const float*)d_in[3];
    const float* wih  = (const float*)d_in[4];
    const float* whh  = (const float*)d_in[5];
    const float* bih  = (const float*)d_in[6];
    const float* bhh  = (const float*)d_in[7];
    const float* wcat = (const float*)d_in[8];
    const float* bcat = (const float*)d_in[9];
    const float* wout = (const float*)d_in[10];
    const float* bout = (const float*)d_in[11];
    float* out = (float*)d_out;
    float* ws  = (float*)d_ws;

    k1_gru_gemm <<<dim3(96, KSL), 256, 0, stream>>>(seq, lh, emb, wih, whh, ws);
    k2_gates    <<<128, 256, 0, stream>>>(lh, bih, bhh, ws, out);
    k3_attn     <<<2048, 256, 0, stream>>>(enc, ws);
    k4_combine  <<<dim3(64, 4), 256, 0, stream>>>(ws, out);
    k5_concat_gemm<<<dim3(32, 4), 256, 0, stream>>>(wcat, ws);
    k5b_concat_fin<<<128, 256, 0, stream>>>(bcat, ws);
    k6_mfma     <<<1571, 128, 0, stream>>>(wout, bout,
                     (const unsigned short*)(ws + CCB_OFF), out);
}

// Round 11
// 583.926 us; speedup vs baseline: 1.1793x; 1.1793x over previous
//
#include <hip/hip_runtime.h>
#include <math.h>

#define NB 64
#define NS 2048
#define NH 512
#define NE 512
#define NV 50257
#define H3 1536
#define KSL 8          // k1 split-K slices
#define NCH 32         // k3 s-chunks per b

// ---- DIAGNOSTIC round 2: disambiguate k1 vs k6 (R10's k3x6 flooded top-5).
// k1 x32 (visible iff k1 >= ~5us), k6 x8 (visible iff k6 >= ~19us), k3 x1.
#define K1REP 32
#define K6REP 8

typedef __attribute__((ext_vector_type(8))) short bf16x8;
typedef __attribute__((ext_vector_type(4))) float f32x4;

// ---- workspace layout (float offsets) ----
#define GI_OFF    0                            // [8][1536][64] gi split-K partials
#define GH_OFF    (GI_OFF + KSL*H3*NB)         // [8][1536][64]
#define HNEW_OFF  (GH_OFF + KSL*H3*NB)         // [64][512]
#define EN_OFF    (HNEW_OFF + NB*NH)           // [64][2048] raw energies
#define PCTX_OFF  (EN_OFF + NB*NS)             // [64][32][512] partial ctx
#define PM_OFF    (PCTX_OFF + NB*NCH*NH)       // [64][32] partial max
#define PL_OFF    (PM_OFF + NB*NCH)            // [64][32] partial sum
#define CPART_OFF (PL_OFF + NB*NCH)            // [4][512][64] concat partials
#define CTX_OFF   (CPART_OFF + 4*NH*NB)        // [64][512]
#define CCB_OFF   (CTX_OFF + NB*NH)            // [64][512] concat_output bf16 (ushort)

// ---- d_out layout (float offsets) ----
#define HID_OFF  ((size_t)NB*NV)
#define ATTN_OFF (HID_OFF + (size_t)NB*NH)

__device__ __forceinline__ unsigned short f2bf(float f) {
    unsigned u = __builtin_bit_cast(unsigned, f);
    u += 0x7FFFu + ((u >> 16) & 1u);   // RNE
    return (unsigned short)(u >> 16);
}

// K1: split-K(8) GRU input GEMMs. AMPLIFIED x32 for diagnosis.
__global__ __launch_bounds__(256) void k1_gru_gemm(
    const int* __restrict__ seq, const float* __restrict__ lh,
    const float* __restrict__ emb, const float* __restrict__ wih,
    const float* __restrict__ whh, float* __restrict__ ws)
{
    __shared__ float xl[64][65];
    __shared__ float hl[64][65];
    __shared__ int idxl[64];
    const int t = threadIdx.x;
    const int b = t & 63;
    const int j0 = __builtin_amdgcn_readfirstlane(blockIdx.x * 16 + (t >> 6) * 4);
    const int k0 = blockIdx.y * 64;
    if (t < 64) idxl[t] = seq[t];
    __syncthreads();
    {   // stage x/h [64][64]: 4 threads per row, 16B chunks
        const int r = t >> 2;
        const int c = (t & 3) * 16;
        #pragma unroll
        for (int q = 0; q < 4; ++q) {
            const float4 xv = *(const float4*)&emb[(size_t)idxl[r] * NE + k0 + c + q*4];
            const float4 hv = *(const float4*)&lh[r * NH + k0 + c + q*4];
            xl[r][c+q*4+0]=xv.x; xl[r][c+q*4+1]=xv.y; xl[r][c+q*4+2]=xv.z; xl[r][c+q*4+3]=xv.w;
            hl[r][c+q*4+0]=hv.x; hl[r][c+q*4+1]=hv.y; hl[r][c+q*4+2]=hv.z; hl[r][c+q*4+3]=hv.w;
        }
    }
    __syncthreads();
    #pragma unroll 1
    for (int rep = 0; rep < K1REP; ++rep) {
        asm volatile("" ::: "memory");   // no cross-rep CSE
        float ai[4] = {0.f,0.f,0.f,0.f};
        float ah[4] = {0.f,0.f,0.f,0.f};
        #pragma unroll 4
        for (int e = 0; e < 64; e += 4) {
            const float x0=xl[b][e], x1=xl[b][e+1], x2=xl[b][e+2], x3=xl[b][e+3];
            const float h0=hl[b][e], h1=hl[b][e+1], h2=hl[b][e+2], h3=hl[b][e+3];
            #pragma unroll
            for (int jj = 0; jj < 4; ++jj) {
                const float4 wi = *(const float4*)&wih[(size_t)(j0+jj)*NE + k0 + e];
                const float4 wh = *(const float4*)&whh[(size_t)(j0+jj)*NH + k0 + e];
                ai[jj] = fmaf(x0,wi.x, fmaf(x1,wi.y, fmaf(x2,wi.z, fmaf(x3,wi.w, ai[jj]))));
                ah[jj] = fmaf(h0,wh.x, fmaf(h1,wh.y, fmaf(h2,wh.z, fmaf(h3,wh.w, ah[jj]))));
            }
        }
        float* gi = ws + GI_OFF + (size_t)blockIdx.y * H3 * NB;
        float* gh = ws + GH_OFF + (size_t)blockIdx.y * H3 * NB;
        #pragma unroll
        for (int jj = 0; jj < 4; ++jj) {
            gi[(j0+jj)*NB + b] = ai[jj];
            gh[(j0+jj)*NB + b] = ah[jj];
        }
    }
}

// K2: combine 8 split-K partials + biases, GRU gate math -> h_new
__global__ __launch_bounds__(256) void k2_gates(
    const float* __restrict__ lh, const float* __restrict__ bih,
    const float* __restrict__ bhh, float* __restrict__ ws, float* __restrict__ out)
{
    const int gid = blockIdx.x * 256 + threadIdx.x;
    const int b = gid & 63;
    const int h = gid >> 6;
    const float* gi = ws + GI_OFF;
    const float* gh = ws + GH_OFF;
    const int P = H3 * NB;
    float ir = bih[h], iz = bih[512+h], inn = bih[1024+h];
    float hr = bhh[h], hz = bhh[512+h], hnn = bhh[1024+h];
    #pragma unroll
    for (int s = 0; s < KSL; ++s) {
        ir  += gi[s*P + h*NB + b];
        iz  += gi[s*P + (512+h)*NB + b];
        inn += gi[s*P + (1024+h)*NB + b];
        hr  += gh[s*P + h*NB + b];
        hz  += gh[s*P + (512+h)*NB + b];
        hnn += gh[s*P + (1024+h)*NB + b];
    }
    const float r = 1.f / (1.f + __expf(-(ir + hr)));
    const float z = 1.f / (1.f + __expf(-(iz + hz)));
    const float nx = inn + r * hnn;
    const float e2 = __expf(-2.f * fabsf(nx));
    const float n = copysignf((1.f - e2) / (1.f + e2), nx);
    const float hnew = (1.f - z) * n + z * lh[b*NH + h];
    ws[HNEW_OFF + b*NH + h] = hnew;
    out[HID_OFF + (size_t)b*NH + h] = hnew;
}

// K3: flash-style attention pass (normal, x1 — measured at roofline in R10).
__global__ __launch_bounds__(256) void k3_attn(
    const float* __restrict__ enc, float* __restrict__ ws)
{
    const int t = threadIdx.x;
    const int w = t >> 6;
    const int l = t & 63;
    const int b = blockIdx.x >> 5;
    const int chunk = blockIdx.x & 31;
    const float* hn = ws + HNEW_OFF + b * NH;
    const float4 hq0 = *(const float4*)&hn[l*4];
    const float4 hq1 = *(const float4*)&hn[256 + l*4];
    const int s0 = chunk * 64 + w * 16;
    const float* rowb = enc + ((size_t)s0 * NB + b) * NH;
    float m = -INFINITY, lsum = 0.f;
    float cx[8] = {0.f,0.f,0.f,0.f,0.f,0.f,0.f,0.f};
    float ekeep = 0.f;
    f32x4 a0 = __builtin_nontemporal_load((const f32x4*)&rowb[l*4]);
    f32x4 a1 = __builtin_nontemporal_load((const f32x4*)&rowb[256 + l*4]);
    for (int i = 0; i < 16; ++i) {
        const f32x4 r0 = a0, r1 = a1;
        if (i < 15) {
            const float* nr = rowb + (size_t)(i+1) * NB * NH;
            a0 = __builtin_nontemporal_load((const f32x4*)&nr[l*4]);
            a1 = __builtin_nontemporal_load((const f32x4*)&nr[256 + l*4]);
        }
        float d = r0.x*hq0.x;
        d = fmaf(r0.y,hq0.y,d); d = fmaf(r0.z,hq0.z,d); d = fmaf(r0.w,hq0.w,d);
        d = fmaf(r1.x,hq1.x,d); d = fmaf(r1.y,hq1.y,d); d = fmaf(r1.z,hq1.z,d); d = fmaf(r1.w,hq1.w,d);
        d += __shfl_xor(d, 32);
        d += __shfl_xor(d, 16);
        d += __shfl_xor(d, 8);
        d += __shfl_xor(d, 4);
        d += __shfl_xor(d, 2);
        d += __shfl_xor(d, 1);
        if (l == i) ekeep = d;
        const float mn = fmaxf(m, d);
        if (mn > m) {   // wave-uniform (d uniform after full reduce)
            const float sc = __expf(m - mn);
            lsum *= sc;
            #pragma unroll
            for (int k = 0; k < 8; ++k) cx[k] *= sc;
            m = mn;
        }
        const float p = __expf(d - m);
        lsum += p;
        cx[0]=fmaf(p,r0.x,cx[0]); cx[1]=fmaf(p,r0.y,cx[1]);
        cx[2]=fmaf(p,r0.z,cx[2]); cx[3]=fmaf(p,r0.w,cx[3]);
        cx[4]=fmaf(p,r1.x,cx[4]); cx[5]=fmaf(p,r1.y,cx[5]);
        cx[6]=fmaf(p,r1.z,cx[6]); cx[7]=fmaf(p,r1.w,cx[7]);
    }
    if (l < 16) ws[EN_OFF + (size_t)b * NS + s0 + l] = ekeep;
    __shared__ float ctxl[4][NH];
    __shared__ float ml[4], ll[4];
    #pragma unroll
    for (int k = 0; k < 4; ++k) {
        ctxl[w][l*4+k]       = cx[k];
        ctxl[w][256 + l*4+k] = cx[4+k];
    }
    if (l == 0) { ml[w] = m; ll[w] = lsum; }
    __syncthreads();
    const float M = fmaxf(fmaxf(ml[0], ml[1]), fmaxf(ml[2], ml[3]));
    const float w0 = __expf(ml[0]-M), w1 = __expf(ml[1]-M);
    const float w2 = __expf(ml[2]-M), w3 = __expf(ml[3]-M);
    for (int e = t; e < NH; e += 256) {
        const float c = ctxl[0][e]*w0 + ctxl[1][e]*w1 + ctxl[2][e]*w2 + ctxl[3][e]*w3;
        ws[PCTX_OFF + ((size_t)b*NCH + chunk)*NH + e] = c;
    }
    if (t == 0) {
        ws[PM_OFF + b*NCH + chunk] = M;
        ws[PL_OFF + b*NCH + chunk] = ll[0]*w0 + ll[1]*w1 + ll[2]*w2 + ll[3]*w3;
    }
}

// K4: combine the 32 partials per b -> ctx (normalized) + attn output.
__global__ __launch_bounds__(256) void k4_combine(
    float* __restrict__ ws, float* __restrict__ out)
{
    const int b = blockIdx.x;
    const int sl = blockIdx.y;
    const int t = threadIdx.x;
    __shared__ float pml[NCH], pll[NCH], pwl[NCH];
    if (t < NCH) { pml[t] = ws[PM_OFF + b*NCH + t]; pll[t] = ws[PL_OFF + b*NCH + t]; }
    __syncthreads();
    float M = -INFINITY;
    #pragma unroll
    for (int c = 0; c < NCH; ++c) M = fmaxf(M, pml[c]);
    if (t < NCH) pwl[t] = __expf(pml[t] - M);
    __syncthreads();
    float L = 0.f;
    #pragma unroll
    for (int c = 0; c < NCH; ++c) L += pll[c] * pwl[c];
    const float invL = 1.f / L;
    const int e = sl * 128 + (t & 127);
    if (t < 128) {
        float acc = 0.f;
        #pragma unroll 8
        for (int c = 0; c < NCH; ++c)
            acc += ws[PCTX_OFF + ((size_t)b*NCH + c)*NH + e] * pwl[c];
        ws[CTX_OFF + b*NH + e] = acc * invL;
    }
    for (int s = sl * 512 + t; s < sl * 512 + 512; s += 256)
        out[ATTN_OFF + (size_t)b*NS + s] = __expf(ws[EN_OFF + (size_t)b*NS + s] - M) * invL;
}

// K5: concat GEMM partials: [64,1024] @ w_concat.T, split-K over 4 chunks of 256
__global__ __launch_bounds__(256) void k5_concat_gemm(
    const float* __restrict__ wcat, float* __restrict__ ws)
{
    __shared__ float al[64][65];
    const int t = threadIdx.x;
    const int b = t & 63;
    const int j0 = __builtin_amdgcn_readfirstlane(blockIdx.x * 16 + (t >> 6) * 4);
    const int kc = blockIdx.y;
    const float* A = ws + ((kc < 2) ? HNEW_OFF : CTX_OFF);
    const int kb = (kc & 1) * 256;
    float acc[4] = {0.f,0.f,0.f,0.f};
    const int c4 = (t & 15) * 4;
    const int r0 = t >> 4;
    for (int ch = 0; ch < 4; ++ch) {
        const int k0 = kb + ch * 64;
        __syncthreads();
        #pragma unroll
        for (int i = 0; i < 4; ++i) {
            const int r = r0 + i * 16;
            const float4 v = *(const float4*)&A[r * NH + k0 + c4];
            al[r][c4+0]=v.x; al[r][c4+1]=v.y; al[r][c4+2]=v.z; al[r][c4+3]=v.w;
        }
        __syncthreads();
        #pragma unroll 4
        for (int e = 0; e < 64; e += 4) {
            const float a0v=al[b][e], a1v=al[b][e+1], a2v=al[b][e+2], a3v=al[b][e+3];
            #pragma unroll
            for (int jj = 0; jj < 4; ++jj) {
                const float4 wq = *(const float4*)&wcat[(size_t)(j0+jj)*1024 + kc*256 + ch*64 + e];
                acc[jj] = fmaf(a0v,wq.x, fmaf(a1v,wq.y, fmaf(a2v,wq.z, fmaf(a3v,wq.w, acc[jj]))));
            }
        }
    }
    #pragma unroll
    for (int jj = 0; jj < 4; ++jj)
        ws[CPART_OFF + ((size_t)kc*NH + j0+jj)*NB + b] = acc[jj];
}

// K5b: sum split-K partials + bias + tanh -> concat_output (bf16 for MFMA k6)
__global__ __launch_bounds__(256) void k5b_concat_fin(
    const float* __restrict__ bcat, float* __restrict__ ws)
{
    const int t = threadIdx.x;
    const int b = t & 63;
    const int j = blockIdx.x * 4 + (t >> 6);
    float v = bcat[j];
    #pragma unroll
    for (int kc = 0; kc < 4; ++kc)
        v += ws[CPART_OFF + ((size_t)kc*NH + j)*NB + b];
    const float e2 = __expf(-2.f * fabsf(v));
    const float th = copysignf((1.f - e2) / (1.f + e2), v);
    unsigned short* ccb = (unsigned short*)(ws + CCB_OFF);
    ccb[b*NH + j] = f2bf(th);
}

// K6: vocab projection via bf16 MFMA (R4-style body). AMPLIFIED x8; wout is
// L3-hot from rep 2 on, so dur/rep(warm) vs cold separates HBM-latency-bound
// from internal-issue-bound. Stores only on the last rep.
__global__ __launch_bounds__(128) void k6_mfma(
    const float* __restrict__ wout, const float* __restrict__ bout,
    const unsigned short* __restrict__ ccb, float* __restrict__ out)
{
    const int t = threadIdx.x;
    const int w = t >> 6;
    const int l = t & 63;
    const int lm = l & 15;
    const int kg = l >> 4;
    const int j = blockIdx.x * 32 + w * 16 + lm;
    const int jc = j < NV ? j : NV - 1;
    const float* wrow = wout + (size_t)jc * NH + kg * 8;
    #pragma unroll 1
    for (int rep = 0; rep < K6REP; ++rep) {
        asm volatile("" ::: "memory");
        f32x4 acc0 = {0.f,0.f,0.f,0.f};
        f32x4 acc1 = {0.f,0.f,0.f,0.f};
        f32x4 acc2 = {0.f,0.f,0.f,0.f};
        f32x4 acc3 = {0.f,0.f,0.f,0.f};
        #pragma unroll 4
        for (int ks = 0; ks < 16; ++ks) {
            const float4 w0 = *(const float4*)(wrow + ks * 32);
            const float4 w1 = *(const float4*)(wrow + ks * 32 + 4);
            bf16x8 bf;
            bf[0] = (short)f2bf(w0.x); bf[1] = (short)f2bf(w0.y);
            bf[2] = (short)f2bf(w0.z); bf[3] = (short)f2bf(w0.w);
            bf[4] = (short)f2bf(w1.x); bf[5] = (short)f2bf(w1.y);
            bf[6] = (short)f2bf(w1.z); bf[7] = (short)f2bf(w1.w);
            const int ka = ks * 32 + kg * 8;
            const bf16x8 a0 = *(const bf16x8*)&ccb[(0*16 + lm) * NH + ka];
            const bf16x8 a1 = *(const bf16x8*)&ccb[(1*16 + lm) * NH + ka];
            const bf16x8 a2 = *(const bf16x8*)&ccb[(2*16 + lm) * NH + ka];
            const bf16x8 a3 = *(const bf16x8*)&ccb[(3*16 + lm) * NH + ka];
            acc0 = __builtin_amdgcn_mfma_f32_16x16x32_bf16(a0, bf, acc0, 0, 0, 0);
            acc1 = __builtin_amdgcn_mfma_f32_16x16x32_bf16(a1, bf, acc1, 0, 0, 0);
            acc2 = __builtin_amdgcn_mfma_f32_16x16x32_bf16(a2, bf, acc2, 0, 0, 0);
            acc3 = __builtin_amdgcn_mfma_f32_16x16x32_bf16(a3, bf, acc3, 0, 0, 0);
        }
        if (rep == K6REP - 1 && j < NV) {
            const float bj = bout[jc];
            #pragma unroll
            for (int r = 0; r < 4; ++r) {
                out[(size_t)(0*16 + kg*4 + r) * NV + j] = acc0[r] + bj;
                out[(size_t)(1*16 + kg*4 + r) * NV + j] = acc1[r] + bj;
                out[(size_t)(2*16 + kg*4 + r) * NV + j] = acc2[r] + bj;
                out[(size_t)(3*16 + kg*4 + r) * NV + j] = acc3[r] + bj;
            }
        }
    }
}

extern "C" void kernel_launch(void* const* d_in, const int* in_sizes, int n_in,
                              void* d_out, int out_size, void* d_ws, size_t ws_size,
                              hipStream_t stream) {
    (void)in_sizes; (void)n_in; (void)out_size; (void)ws_size;
    const int*   seq  = (const int*)  d_in[0];
    const float* lh   = (const float*)d_in[1];
    const float* enc  = (const float*)d_in[2];
    const float* emb  = (const float*)d_in[3];
    const float* wih  = (const float*)d_in[4];
    const float* whh  = (const float*)d_in[5];
    const float* bih  = (const float*)d_in[6];
    const float* bhh  = (const float*)d_in[7];
    const float* wcat = (const float*)d_in[8];
    const float* bcat = (const float*)d_in[9];
    const float* wout = (const float*)d_in[10];
    const float* bout = (const float*)d_in[11];
    float* out = (float*)d_out;
    float* ws  = (float*)d_ws;

    k1_gru_gemm <<<dim3(96, KSL), 256, 0, stream>>>(seq, lh, emb, wih, whh, ws);
    k2_gates    <<<128, 256, 0, stream>>>(lh, bih, bhh, ws, out);
    k3_attn     <<<2048, 256, 0, stream>>>(enc, ws);
    k4_combine  <<<dim3(64, 4), 256, 0, stream>>>(ws, out);
    k5_concat_gemm<<<dim3(32, 4), 256, 0, stream>>>(wcat, ws);
    k5b_concat_fin<<<128, 256, 0, stream>>>(bcat, ws);
    k6_mfma     <<<1571, 128, 0, stream>>>(wout, bout,
                     (const unsigned short*)(ws + CCB_OFF), out);
}

// Round 12
// 130.634 us; speedup vs baseline: 5.2715x; 4.4699x over previous
//
#include <hip/hip_runtime.h>
#include <math.h>

#define NB 64
#define NS 2048
#define NH 512
#define NE 512
#define NV 50257
#define H3 1536
#define KSL 8          // k1 split-K slices
#define NCH 32         // k3 s-chunks per b

typedef __attribute__((ext_vector_type(8))) short bf16x8;
typedef __attribute__((ext_vector_type(4))) float f32x4;

// ---- workspace layout (float offsets) ----
#define GI_OFF    0                            // [8][1536][64] gi split-K partials
#define GH_OFF    (GI_OFF + KSL*H3*NB)         // [8][1536][64]
#define HNEW_OFF  (GH_OFF + KSL*H3*NB)         // [64][512]
#define EN_OFF    (HNEW_OFF + NB*NH)           // [64][2048] raw energies
#define PCTX_OFF  (EN_OFF + NB*NS)             // [64][32][512] partial ctx
#define PM_OFF    (PCTX_OFF + NB*NCH*NH)       // [64][32] partial max
#define PL_OFF    (PM_OFF + NB*NCH)            // [64][32] partial sum
#define CPART_OFF (PL_OFF + NB*NCH)            // [4][512][64] concat partials
#define CTX_OFF   (CPART_OFF + 4*NH*NB)        // [64][512]
#define CCB_OFF   (CTX_OFF + NB*NH)            // [64][512] concat_output bf16 (ushort)

// ---- d_out layout (float offsets) ----
#define HID_OFF  ((size_t)NB*NV)
#define ATTN_OFF (HID_OFF + (size_t)NB*NH)

__device__ __forceinline__ unsigned short f2bf(float f) {
    unsigned u = __builtin_bit_cast(unsigned, f);
    u += 0x7FFFu + ((u >> 16) & 1u);   // RNE
    return (unsigned short)(u >> 16);
}

// K1: split-K(8) GRU input GEMMs. grid (96 j-tiles, 8 k-slices). lane=b, 4 j/thread.
__global__ __launch_bounds__(256) void k1_gru_gemm(
    const int* __restrict__ seq, const float* __restrict__ lh,
    const float* __restrict__ emb, const float* __restrict__ wih,
    const float* __restrict__ whh, float* __restrict__ ws)
{
    __shared__ float xl[64][65];
    __shared__ float hl[64][65];
    __shared__ int idxl[64];
    const int t = threadIdx.x;
    const int b = t & 63;
    const int j0 = __builtin_amdgcn_readfirstlane(blockIdx.x * 16 + (t >> 6) * 4);
    const int k0 = blockIdx.y * 64;
    if (t < 64) idxl[t] = seq[t];
    __syncthreads();
    {   // stage x/h [64][64]: 4 threads per row, 16B chunks
        const int r = t >> 2;
        const int c = (t & 3) * 16;
        #pragma unroll
        for (int q = 0; q < 4; ++q) {
            const float4 xv = *(const float4*)&emb[(size_t)idxl[r] * NE + k0 + c + q*4];
            const float4 hv = *(const float4*)&lh[r * NH + k0 + c + q*4];
            xl[r][c+q*4+0]=xv.x; xl[r][c+q*4+1]=xv.y; xl[r][c+q*4+2]=xv.z; xl[r][c+q*4+3]=xv.w;
            hl[r][c+q*4+0]=hv.x; hl[r][c+q*4+1]=hv.y; hl[r][c+q*4+2]=hv.z; hl[r][c+q*4+3]=hv.w;
        }
    }
    __syncthreads();
    float ai[4] = {0.f,0.f,0.f,0.f};
    float ah[4] = {0.f,0.f,0.f,0.f};
    #pragma unroll 4
    for (int e = 0; e < 64; e += 4) {
        const float x0=xl[b][e], x1=xl[b][e+1], x2=xl[b][e+2], x3=xl[b][e+3];
        const float h0=hl[b][e], h1=hl[b][e+1], h2=hl[b][e+2], h3=hl[b][e+3];
        #pragma unroll
        for (int jj = 0; jj < 4; ++jj) {
            const float4 wi = *(const float4*)&wih[(size_t)(j0+jj)*NE + k0 + e];
            const float4 wh = *(const float4*)&whh[(size_t)(j0+jj)*NH + k0 + e];
            ai[jj] = fmaf(x0,wi.x, fmaf(x1,wi.y, fmaf(x2,wi.z, fmaf(x3,wi.w, ai[jj]))));
            ah[jj] = fmaf(h0,wh.x, fmaf(h1,wh.y, fmaf(h2,wh.z, fmaf(h3,wh.w, ah[jj]))));
        }
    }
    float* gi = ws + GI_OFF + (size_t)blockIdx.y * H3 * NB;
    float* gh = ws + GH_OFF + (size_t)blockIdx.y * H3 * NB;
    #pragma unroll
    for (int jj = 0; jj < 4; ++jj) {
        gi[(j0+jj)*NB + b] = ai[jj];
        gh[(j0+jj)*NB + b] = ah[jj];
    }
}

// K2: combine 8 split-K partials + biases, GRU gate math -> h_new
__global__ __launch_bounds__(256) void k2_gates(
    const float* __restrict__ lh, const float* __restrict__ bih,
    const float* __restrict__ bhh, float* __restrict__ ws, float* __restrict__ out)
{
    const int gid = blockIdx.x * 256 + threadIdx.x;
    const int b = gid & 63;
    const int h = gid >> 6;
    const float* gi = ws + GI_OFF;
    const float* gh = ws + GH_OFF;
    const int P = H3 * NB;
    float ir = bih[h], iz = bih[512+h], inn = bih[1024+h];
    float hr = bhh[h], hz = bhh[512+h], hnn = bhh[1024+h];
    #pragma unroll
    for (int s = 0; s < KSL; ++s) {
        ir  += gi[s*P + h*NB + b];
        iz  += gi[s*P + (512+h)*NB + b];
        inn += gi[s*P + (1024+h)*NB + b];
        hr  += gh[s*P + h*NB + b];
        hz  += gh[s*P + (512+h)*NB + b];
        hnn += gh[s*P + (1024+h)*NB + b];
    }
    const float r = 1.f / (1.f + __expf(-(ir + hr)));
    const float z = 1.f / (1.f + __expf(-(iz + hz)));
    const float nx = inn + r * hnn;
    const float e2 = __expf(-2.f * fabsf(nx));
    const float n = copysignf((1.f - e2) / (1.f + e2), nx);
    const float hnew = (1.f - z) * n + z * lh[b*NH + h];
    ws[HNEW_OFF + b*NH + h] = hnew;
    out[HID_OFF + (size_t)b*NH + h] = hnew;
}

// K3: flash-style attention pass. grid 2048 = b(64) x chunk(32); at HBM roofline
// (R10 diag: 45.6us/rep ~ 5.9 TB/s effective). Do not touch.
__global__ __launch_bounds__(256) void k3_attn(
    const float* __restrict__ enc, float* __restrict__ ws)
{
    const int t = threadIdx.x;
    const int w = t >> 6;
    const int l = t & 63;
    const int b = blockIdx.x >> 5;
    const int chunk = blockIdx.x & 31;
    const float* hn = ws + HNEW_OFF + b * NH;
    const float4 hq0 = *(const float4*)&hn[l*4];
    const float4 hq1 = *(const float4*)&hn[256 + l*4];
    const int s0 = chunk * 64 + w * 16;
    const float* rowb = enc + ((size_t)s0 * NB + b) * NH;
    float m = -INFINITY, lsum = 0.f;
    float cx[8] = {0.f,0.f,0.f,0.f,0.f,0.f,0.f,0.f};
    float ekeep = 0.f;
    f32x4 a0 = __builtin_nontemporal_load((const f32x4*)&rowb[l*4]);
    f32x4 a1 = __builtin_nontemporal_load((const f32x4*)&rowb[256 + l*4]);
    for (int i = 0; i < 16; ++i) {
        const f32x4 r0 = a0, r1 = a1;
        if (i < 15) {
            const float* nr = rowb + (size_t)(i+1) * NB * NH;
            a0 = __builtin_nontemporal_load((const f32x4*)&nr[l*4]);
            a1 = __builtin_nontemporal_load((const f32x4*)&nr[256 + l*4]);
        }
        float d = r0.x*hq0.x;
        d = fmaf(r0.y,hq0.y,d); d = fmaf(r0.z,hq0.z,d); d = fmaf(r0.w,hq0.w,d);
        d = fmaf(r1.x,hq1.x,d); d = fmaf(r1.y,hq1.y,d); d = fmaf(r1.z,hq1.z,d); d = fmaf(r1.w,hq1.w,d);
        d += __shfl_xor(d, 32);
        d += __shfl_xor(d, 16);
        d += __shfl_xor(d, 8);
        d += __shfl_xor(d, 4);
        d += __shfl_xor(d, 2);
        d += __shfl_xor(d, 1);
        if (l == i) ekeep = d;
        const float mn = fmaxf(m, d);
        if (mn > m) {   // wave-uniform (d uniform after full reduce)
            const float sc = __expf(m - mn);
            lsum *= sc;
            #pragma unroll
            for (int k = 0; k < 8; ++k) cx[k] *= sc;
            m = mn;
        }
        const float p = __expf(d - m);
        lsum += p;
        cx[0]=fmaf(p,r0.x,cx[0]); cx[1]=fmaf(p,r0.y,cx[1]);
        cx[2]=fmaf(p,r0.z,cx[2]); cx[3]=fmaf(p,r0.w,cx[3]);
        cx[4]=fmaf(p,r1.x,cx[4]); cx[5]=fmaf(p,r1.y,cx[5]);
        cx[6]=fmaf(p,r1.z,cx[6]); cx[7]=fmaf(p,r1.w,cx[7]);
    }
    if (l < 16) ws[EN_OFF + (size_t)b * NS + s0 + l] = ekeep;
    __shared__ float ctxl[4][NH];
    __shared__ float ml[4], ll[4];
    #pragma unroll
    for (int k = 0; k < 4; ++k) {
        ctxl[w][l*4+k]       = cx[k];
        ctxl[w][256 + l*4+k] = cx[4+k];
    }
    if (l == 0) { ml[w] = m; ll[w] = lsum; }
    __syncthreads();
    const float M = fmaxf(fmaxf(ml[0], ml[1]), fmaxf(ml[2], ml[3]));
    const float w0 = __expf(ml[0]-M), w1 = __expf(ml[1]-M);
    const float w2 = __expf(ml[2]-M), w3 = __expf(ml[3]-M);
    for (int e = t; e < NH; e += 256) {
        const float c = ctxl[0][e]*w0 + ctxl[1][e]*w1 + ctxl[2][e]*w2 + ctxl[3][e]*w3;
        ws[PCTX_OFF + ((size_t)b*NCH + chunk)*NH + e] = c;
    }
    if (t == 0) {
        ws[PM_OFF + b*NCH + chunk] = M;
        ws[PL_OFF + b*NCH + chunk] = ll[0]*w0 + ll[1]*w1 + ll[2]*w2 + ll[3]*w3;
    }
}

// K4: combine the 32 partials per b -> ctx (normalized) + attn output.
__global__ __launch_bounds__(256) void k4_combine(
    float* __restrict__ ws, float* __restrict__ out)
{
    const int b = blockIdx.x;
    const int sl = blockIdx.y;
    const int t = threadIdx.x;
    __shared__ float pml[NCH], pll[NCH], pwl[NCH];
    if (t < NCH) { pml[t] = ws[PM_OFF + b*NCH + t]; pll[t] = ws[PL_OFF + b*NCH + t]; }
    __syncthreads();
    float M = -INFINITY;
    #pragma unroll
    for (int c = 0; c < NCH; ++c) M = fmaxf(M, pml[c]);
    if (t < NCH) pwl[t] = __expf(pml[t] - M);
    __syncthreads();
    float L = 0.f;
    #pragma unroll
    for (int c = 0; c < NCH; ++c) L += pll[c] * pwl[c];
    const float invL = 1.f / L;
    const int e = sl * 128 + (t & 127);
    if (t < 128) {
        float acc = 0.f;
        #pragma unroll 8
        for (int c = 0; c < NCH; ++c)
            acc += ws[PCTX_OFF + ((size_t)b*NCH + c)*NH + e] * pwl[c];
        ws[CTX_OFF + b*NH + e] = acc * invL;
    }
    for (int s = sl * 512 + t; s < sl * 512 + 512; s += 256)
        out[ATTN_OFF + (size_t)b*NS + s] = __expf(ws[EN_OFF + (size_t)b*NS + s] - M) * invL;
}

// K5: concat GEMM partials: [64,1024] @ w_concat.T, split-K over 4 chunks of 256
__global__ __launch_bounds__(256) void k5_concat_gemm(
    const float* __restrict__ wcat, float* __restrict__ ws)
{
    __shared__ float al[64][65];
    const int t = threadIdx.x;
    const int b = t & 63;
    const int j0 = __builtin_amdgcn_readfirstlane(blockIdx.x * 16 + (t >> 6) * 4);
    const int kc = blockIdx.y;
    const float* A = ws + ((kc < 2) ? HNEW_OFF : CTX_OFF);
    const int kb = (kc & 1) * 256;
    float acc[4] = {0.f,0.f,0.f,0.f};
    const int c4 = (t & 15) * 4;
    const int r0 = t >> 4;
    for (int ch = 0; ch < 4; ++ch) {
        const int k0 = kb + ch * 64;
        __syncthreads();
        #pragma unroll
        for (int i = 0; i < 4; ++i) {
            const int r = r0 + i * 16;
            const float4 v = *(const float4*)&A[r * NH + k0 + c4];
            al[r][c4+0]=v.x; al[r][c4+1]=v.y; al[r][c4+2]=v.z; al[r][c4+3]=v.w;
        }
        __syncthreads();
        #pragma unroll 4
        for (int e = 0; e < 64; e += 4) {
            const float a0v=al[b][e], a1v=al[b][e+1], a2v=al[b][e+2], a3v=al[b][e+3];
            #pragma unroll
            for (int jj = 0; jj < 4; ++jj) {
                const float4 wq = *(const float4*)&wcat[(size_t)(j0+jj)*1024 + kc*256 + ch*64 + e];
                acc[jj] = fmaf(a0v,wq.x, fmaf(a1v,wq.y, fmaf(a2v,wq.z, fmaf(a3v,wq.w, acc[jj]))));
            }
        }
    }
    #pragma unroll
    for (int jj = 0; jj < 4; ++jj)
        ws[CPART_OFF + ((size_t)kc*NH + j0+jj)*NB + b] = acc[jj];
}

// K5b: sum split-K partials + bias + tanh -> concat_output (bf16 for MFMA k6)
__global__ __launch_bounds__(256) void k5b_concat_fin(
    const float* __restrict__ bcat, float* __restrict__ ws)
{
    const int t = threadIdx.x;
    const int b = t & 63;
    const int j = blockIdx.x * 4 + (t >> 6);
    float v = bcat[j];
    #pragma unroll
    for (int kc = 0; kc < 4; ++kc)
        v += ws[CPART_OFF + ((size_t)kc*NH + j)*NB + b];
    const float e2 = __expf(-2.f * fabsf(v));
    const float th = copysignf((1.f - e2) / (1.f + e2), v);
    unsigned short* ccb = (unsigned short*)(ws + CCB_OFF);
    ccb[b*NH + j] = f2bf(th);
}

// K6: vocab projection via bf16 MFMA with IN-BLOCK SPLIT-K.
// R11 diag: k6 = 38.5us with hbm 17% / VALU 7% / MFMA 3.3% / occ 32% ->
// latency-bound at 3.07 waves/SIMD (grid-limited). Fix: 256-thread blocks,
// waves {0,1} do K[0:256) for the block's 32 j, waves {2,3} do K[256:512);
// partials combined through LDS (fixed order -> deterministic). Same grid ->
// 2x waves/CU + half-length serial chains per wave.
__global__ __launch_bounds__(256) void k6_mfma(
    const float* __restrict__ wout, const float* __restrict__ bout,
    const unsigned short* __restrict__ ccb, float* __restrict__ out)
{
    __shared__ float pk[2][16][64];   // [j-tile][frag elem][lane]
    const int t = threadIdx.x;
    const int w = t >> 6;
    const int l = t & 63;
    const int lm = l & 15;
    const int kg = l >> 4;
    const int wj = w & 1;      // j-tile within block
    const int wk = w >> 1;     // K-half
    const int j = blockIdx.x * 32 + wj * 16 + lm;
    const int jc = j < NV ? j : NV - 1;
    const float* wrow = wout + (size_t)jc * NH + kg * 8;
    f32x4 acc0 = {0.f,0.f,0.f,0.f};
    f32x4 acc1 = {0.f,0.f,0.f,0.f};
    f32x4 acc2 = {0.f,0.f,0.f,0.f};
    f32x4 acc3 = {0.f,0.f,0.f,0.f};
    #pragma unroll
    for (int ks8 = 0; ks8 < 8; ++ks8) {   // this wave's K-half: 8 x 32 k
        const int ks = wk * 8 + ks8;
        const float4 w0 = *(const float4*)(wrow + ks * 32);
        const float4 w1 = *(const float4*)(wrow + ks * 32 + 4);
        bf16x8 bf;
        bf[0] = (short)f2bf(w0.x); bf[1] = (short)f2bf(w0.y);
        bf[2] = (short)f2bf(w0.z); bf[3] = (short)f2bf(w0.w);
        bf[4] = (short)f2bf(w1.x); bf[5] = (short)f2bf(w1.y);
        bf[6] = (short)f2bf(w1.z); bf[7] = (short)f2bf(w1.w);
        const int ka = ks * 32 + kg * 8;
        const bf16x8 a0 = *(const bf16x8*)&ccb[(0*16 + lm) * NH + ka];
        const bf16x8 a1 = *(const bf16x8*)&ccb[(1*16 + lm) * NH + ka];
        const bf16x8 a2 = *(const bf16x8*)&ccb[(2*16 + lm) * NH + ka];
        const bf16x8 a3 = *(const bf16x8*)&ccb[(3*16 + lm) * NH + ka];
        acc0 = __builtin_amdgcn_mfma_f32_16x16x32_bf16(a0, bf, acc0, 0, 0, 0);
        acc1 = __builtin_amdgcn_mfma_f32_16x16x32_bf16(a1, bf, acc1, 0, 0, 0);
        acc2 = __builtin_amdgcn_mfma_f32_16x16x32_bf16(a2, bf, acc2, 0, 0, 0);
        acc3 = __builtin_amdgcn_mfma_f32_16x16x32_bf16(a3, bf, acc3, 0, 0, 0);
    }
    if (wk == 1) {   // upper K-half: publish partials ([frag][lane] = conflict-free)
        #pragma unroll
        for (int r = 0; r < 4; ++r) {
            pk[wj][0  + r][l] = acc0[r];
            pk[wj][4  + r][l] = acc1[r];
            pk[wj][8  + r][l] = acc2[r];
            pk[wj][12 + r][l] = acc3[r];
        }
    }
    __syncthreads();
    if (wk == 0 && j < NV) {
        const float bj = bout[jc];
        #pragma unroll
        for (int r = 0; r < 4; ++r) {
            out[(size_t)(0*16 + kg*4 + r) * NV + j] = acc0[r] + pk[wj][0  + r][l] + bj;
            out[(size_t)(1*16 + kg*4 + r) * NV + j] = acc1[r] + pk[wj][4  + r][l] + bj;
            out[(size_t)(2*16 + kg*4 + r) * NV + j] = acc2[r] + pk[wj][8  + r][l] + bj;
            out[(size_t)(3*16 + kg*4 + r) * NV + j] = acc3[r] + pk[wj][12 + r][l] + bj;
        }
    }
}

extern "C" void kernel_launch(void* const* d_in, const int* in_sizes, int n_in,
                              void* d_out, int out_size, void* d_ws, size_t ws_size,
                              hipStream_t stream) {
    (void)in_sizes; (void)n_in; (void)out_size; (void)ws_size;
    const int*   seq  = (const int*)  d_in[0];
    const float* lh   = (const float*)d_in[1];
    const float* enc  = (const float*)d_in[2];
    const float* emb  = (const float*)d_in[3];
    const float* wih  = (const float*)d_in[4];
    const float* whh  = (const float*)d_in[5];
    const float* bih  = (const float*)d_in[6];
    const float* bhh  = (const float*)d_in[7];
    const float* wcat = (const float*)d_in[8];
    const float* bcat = (const float*)d_in[9];
    const float* wout = (const float*)d_in[10];
    const float* bout = (const float*)d_in[11];
    float* out = (float*)d_out;
    float* ws  = (float*)d_ws;

    k1_gru_gemm <<<dim3(96, KSL), 256, 0, stream>>>(seq, lh, emb, wih, whh, ws);
    k2_gates    <<<128, 256, 0, stream>>>(lh, bih, bhh, ws, out);
    k3_attn     <<<2048, 256, 0, stream>>>(enc, ws);
    k4_combine  <<<dim3(64, 4), 256, 0, stream>>>(ws, out);
    k5_concat_gemm<<<dim3(32, 4), 256, 0, stream>>>(wcat, ws);
    k5b_concat_fin<<<128, 256, 0, stream>>>(bcat, ws);
    k6_mfma     <<<1571, 256, 0, stream>>>(wout, bout,
                     (const unsigned short*)(ws + CCB_OFF), out);
}

// Round 13
// 114.017 us; speedup vs baseline: 6.0398x; 1.1457x over previous
//
#include <hip/hip_runtime.h>
#include <math.h>

#define NB 64
#define NS 2048
#define NH 512
#define NE 512
#define NV 50257
#define H3 1536
#define KSL 8          // k1 split-K slices
#define NCH 32         // k3 s-chunks per b

typedef __attribute__((ext_vector_type(8))) short bf16x8;
typedef __attribute__((ext_vector_type(4))) float f32x4;

// ---- workspace layout (float offsets) ----
#define GI_OFF    0                            // [8][1536][64] gi split-K partials
#define GH_OFF    (GI_OFF + KSL*H3*NB)         // [8][1536][64]
#define HNEW_OFF  (GH_OFF + KSL*H3*NB)         // [64][512]
#define EN_OFF    (HNEW_OFF + NB*NH)           // [64][2048] raw energies
#define PCTX_OFF  (EN_OFF + NB*NS)             // [64][32][512] partial ctx
#define PM_OFF    (PCTX_OFF + NB*NCH*NH)       // [64][32] partial max
#define PL_OFF    (PM_OFF + NB*NCH)            // [64][32] partial sum
#define CPART_OFF (PL_OFF + NB*NCH)            // [4][512][64] concat partials
#define CTX_OFF   (CPART_OFF + 4*NH*NB)        // [64][512]
#define CCB_OFF   (CTX_OFF + NB*NH)            // [64][512] concat_output bf16 (ushort)

// ---- d_out layout (float offsets) ----
#define HID_OFF  ((size_t)NB*NV)
#define ATTN_OFF (HID_OFF + (size_t)NB*NH)

__device__ __forceinline__ unsigned short f2bf(float f) {
    unsigned u = __builtin_bit_cast(unsigned, f);
    u += 0x7FFFu + ((u >> 16) & 1u);   // RNE
    return (unsigned short)(u >> 16);
}

// K1: split-K(8) GRU input GEMMs. grid (96 j-tiles, 8 k-slices). lane=b, 4 j/thread.
__global__ __launch_bounds__(256) void k1_gru_gemm(
    const int* __restrict__ seq, const float* __restrict__ lh,
    const float* __restrict__ emb, const float* __restrict__ wih,
    const float* __restrict__ whh, float* __restrict__ ws)
{
    __shared__ float xl[64][65];
    __shared__ float hl[64][65];
    __shared__ int idxl[64];
    const int t = threadIdx.x;
    const int b = t & 63;
    const int j0 = __builtin_amdgcn_readfirstlane(blockIdx.x * 16 + (t >> 6) * 4);
    const int k0 = blockIdx.y * 64;
    if (t < 64) idxl[t] = seq[t];
    __syncthreads();
    {   // stage x/h [64][64]: 4 threads per row, 16B chunks
        const int r = t >> 2;
        const int c = (t & 3) * 16;
        #pragma unroll
        for (int q = 0; q < 4; ++q) {
            const float4 xv = *(const float4*)&emb[(size_t)idxl[r] * NE + k0 + c + q*4];
            const float4 hv = *(const float4*)&lh[r * NH + k0 + c + q*4];
            xl[r][c+q*4+0]=xv.x; xl[r][c+q*4+1]=xv.y; xl[r][c+q*4+2]=xv.z; xl[r][c+q*4+3]=xv.w;
            hl[r][c+q*4+0]=hv.x; hl[r][c+q*4+1]=hv.y; hl[r][c+q*4+2]=hv.z; hl[r][c+q*4+3]=hv.w;
        }
    }
    __syncthreads();
    float ai[4] = {0.f,0.f,0.f,0.f};
    float ah[4] = {0.f,0.f,0.f,0.f};
    #pragma unroll 4
    for (int e = 0; e < 64; e += 4) {
        const float x0=xl[b][e], x1=xl[b][e+1], x2=xl[b][e+2], x3=xl[b][e+3];
        const float h0=hl[b][e], h1=hl[b][e+1], h2=hl[b][e+2], h3=hl[b][e+3];
        #pragma unroll
        for (int jj = 0; jj < 4; ++jj) {
            const float4 wi = *(const float4*)&wih[(size_t)(j0+jj)*NE + k0 + e];
            const float4 wh = *(const float4*)&whh[(size_t)(j0+jj)*NH + k0 + e];
            ai[jj] = fmaf(x0,wi.x, fmaf(x1,wi.y, fmaf(x2,wi.z, fmaf(x3,wi.w, ai[jj]))));
            ah[jj] = fmaf(h0,wh.x, fmaf(h1,wh.y, fmaf(h2,wh.z, fmaf(h3,wh.w, ah[jj]))));
        }
    }
    float* gi = ws + GI_OFF + (size_t)blockIdx.y * H3 * NB;
    float* gh = ws + GH_OFF + (size_t)blockIdx.y * H3 * NB;
    #pragma unroll
    for (int jj = 0; jj < 4; ++jj) {
        gi[(j0+jj)*NB + b] = ai[jj];
        gh[(j0+jj)*NB + b] = ah[jj];
    }
}

// K2: combine 8 split-K partials + biases, GRU gate math -> h_new
__global__ __launch_bounds__(256) void k2_gates(
    const float* __restrict__ lh, const float* __restrict__ bih,
    const float* __restrict__ bhh, float* __restrict__ ws, float* __restrict__ out)
{
    const int gid = blockIdx.x * 256 + threadIdx.x;
    const int b = gid & 63;
    const int h = gid >> 6;
    const float* gi = ws + GI_OFF;
    const float* gh = ws + GH_OFF;
    const int P = H3 * NB;
    float ir = bih[h], iz = bih[512+h], inn = bih[1024+h];
    float hr = bhh[h], hz = bhh[512+h], hnn = bhh[1024+h];
    #pragma unroll
    for (int s = 0; s < KSL; ++s) {
        ir  += gi[s*P + h*NB + b];
        iz  += gi[s*P + (512+h)*NB + b];
        inn += gi[s*P + (1024+h)*NB + b];
        hr  += gh[s*P + h*NB + b];
        hz  += gh[s*P + (512+h)*NB + b];
        hnn += gh[s*P + (1024+h)*NB + b];
    }
    const float r = 1.f / (1.f + __expf(-(ir + hr)));
    const float z = 1.f / (1.f + __expf(-(iz + hz)));
    const float nx = inn + r * hnn;
    const float e2 = __expf(-2.f * fabsf(nx));
    const float n = copysignf((1.f - e2) / (1.f + e2), nx);
    const float hnew = (1.f - z) * n + z * lh[b*NH + h];
    ws[HNEW_OFF + b*NH + h] = hnew;
    out[HID_OFF + (size_t)b*NH + h] = hnew;
}

// K3: flash-style attention pass. grid 2048 = b(64) x chunk(32); at HBM roofline
// (R10 diag: 45.6us/rep ~ 5.9 TB/s effective). Do not touch.
__global__ __launch_bounds__(256) void k3_attn(
    const float* __restrict__ enc, float* __restrict__ ws)
{
    const int t = threadIdx.x;
    const int w = t >> 6;
    const int l = t & 63;
    const int b = blockIdx.x >> 5;
    const int chunk = blockIdx.x & 31;
    const float* hn = ws + HNEW_OFF + b * NH;
    const float4 hq0 = *(const float4*)&hn[l*4];
    const float4 hq1 = *(const float4*)&hn[256 + l*4];
    const int s0 = chunk * 64 + w * 16;
    const float* rowb = enc + ((size_t)s0 * NB + b) * NH;
    float m = -INFINITY, lsum = 0.f;
    float cx[8] = {0.f,0.f,0.f,0.f,0.f,0.f,0.f,0.f};
    float ekeep = 0.f;
    f32x4 a0 = __builtin_nontemporal_load((const f32x4*)&rowb[l*4]);
    f32x4 a1 = __builtin_nontemporal_load((const f32x4*)&rowb[256 + l*4]);
    for (int i = 0; i < 16; ++i) {
        const f32x4 r0 = a0, r1 = a1;
        if (i < 15) {
            const float* nr = rowb + (size_t)(i+1) * NB * NH;
            a0 = __builtin_nontemporal_load((const f32x4*)&nr[l*4]);
            a1 = __builtin_nontemporal_load((const f32x4*)&nr[256 + l*4]);
        }
        float d = r0.x*hq0.x;
        d = fmaf(r0.y,hq0.y,d); d = fmaf(r0.z,hq0.z,d); d = fmaf(r0.w,hq0.w,d);
        d = fmaf(r1.x,hq1.x,d); d = fmaf(r1.y,hq1.y,d); d = fmaf(r1.z,hq1.z,d); d = fmaf(r1.w,hq1.w,d);
        d += __shfl_xor(d, 32);
        d += __shfl_xor(d, 16);
        d += __shfl_xor(d, 8);
        d += __shfl_xor(d, 4);
        d += __shfl_xor(d, 2);
        d += __shfl_xor(d, 1);
        if (l == i) ekeep = d;
        const float mn = fmaxf(m, d);
        if (mn > m) {   // wave-uniform (d uniform after full reduce)
            const float sc = __expf(m - mn);
            lsum *= sc;
            #pragma unroll
            for (int k = 0; k < 8; ++k) cx[k] *= sc;
            m = mn;
        }
        const float p = __expf(d - m);
        lsum += p;
        cx[0]=fmaf(p,r0.x,cx[0]); cx[1]=fmaf(p,r0.y,cx[1]);
        cx[2]=fmaf(p,r0.z,cx[2]); cx[3]=fmaf(p,r0.w,cx[3]);
        cx[4]=fmaf(p,r1.x,cx[4]); cx[5]=fmaf(p,r1.y,cx[5]);
        cx[6]=fmaf(p,r1.z,cx[6]); cx[7]=fmaf(p,r1.w,cx[7]);
    }
    if (l < 16) ws[EN_OFF + (size_t)b * NS + s0 + l] = ekeep;
    __shared__ float ctxl[4][NH];
    __shared__ float ml[4], ll[4];
    #pragma unroll
    for (int k = 0; k < 4; ++k) {
        ctxl[w][l*4+k]       = cx[k];
        ctxl[w][256 + l*4+k] = cx[4+k];
    }
    if (l == 0) { ml[w] = m; ll[w] = lsum; }
    __syncthreads();
    const float M = fmaxf(fmaxf(ml[0], ml[1]), fmaxf(ml[2], ml[3]));
    const float w0 = __expf(ml[0]-M), w1 = __expf(ml[1]-M);
    const float w2 = __expf(ml[2]-M), w3 = __expf(ml[3]-M);
    for (int e = t; e < NH; e += 256) {
        const float c = ctxl[0][e]*w0 + ctxl[1][e]*w1 + ctxl[2][e]*w2 + ctxl[3][e]*w3;
        ws[PCTX_OFF + ((size_t)b*NCH + chunk)*NH + e] = c;
    }
    if (t == 0) {
        ws[PM_OFF + b*NCH + chunk] = M;
        ws[PL_OFF + b*NCH + chunk] = ll[0]*w0 + ll[1]*w1 + ll[2]*w2 + ll[3]*w3;
    }
}

// K4: combine the 32 partials per b -> ctx (normalized) + attn output.
__global__ __launch_bounds__(256) void k4_combine(
    float* __restrict__ ws, float* __restrict__ out)
{
    const int b = blockIdx.x;
    const int sl = blockIdx.y;
    const int t = threadIdx.x;
    __shared__ float pml[NCH], pll[NCH], pwl[NCH];
    if (t < NCH) { pml[t] = ws[PM_OFF + b*NCH + t]; pll[t] = ws[PL_OFF + b*NCH + t]; }
    __syncthreads();
    float M = -INFINITY;
    #pragma unroll
    for (int c = 0; c < NCH; ++c) M = fmaxf(M, pml[c]);
    if (t < NCH) pwl[t] = __expf(pml[t] - M);
    __syncthreads();
    float L = 0.f;
    #pragma unroll
    for (int c = 0; c < NCH; ++c) L += pll[c] * pwl[c];
    const float invL = 1.f / L;
    const int e = sl * 128 + (t & 127);
    if (t < 128) {
        float acc = 0.f;
        #pragma unroll 8
        for (int c = 0; c < NCH; ++c)
            acc += ws[PCTX_OFF + ((size_t)b*NCH + c)*NH + e] * pwl[c];
        ws[CTX_OFF + b*NH + e] = acc * invL;
    }
    for (int s = sl * 512 + t; s < sl * 512 + 512; s += 256)
        out[ATTN_OFF + (size_t)b*NS + s] = __expf(ws[EN_OFF + (size_t)b*NS + s] - M) * invL;
}

// K5: concat GEMM partials: [64,1024] @ w_concat.T, split-K over 4 chunks of 256
__global__ __launch_bounds__(256) void k5_concat_gemm(
    const float* __restrict__ wcat, float* __restrict__ ws)
{
    __shared__ float al[64][65];
    const int t = threadIdx.x;
    const int b = t & 63;
    const int j0 = __builtin_amdgcn_readfirstlane(blockIdx.x * 16 + (t >> 6) * 4);
    const int kc = blockIdx.y;
    const float* A = ws + ((kc < 2) ? HNEW_OFF : CTX_OFF);
    const int kb = (kc & 1) * 256;
    float acc[4] = {0.f,0.f,0.f,0.f};
    const int c4 = (t & 15) * 4;
    const int r0 = t >> 4;
    for (int ch = 0; ch < 4; ++ch) {
        const int k0 = kb + ch * 64;
        __syncthreads();
        #pragma unroll
        for (int i = 0; i < 4; ++i) {
            const int r = r0 + i * 16;
            const float4 v = *(const float4*)&A[r * NH + k0 + c4];
            al[r][c4+0]=v.x; al[r][c4+1]=v.y; al[r][c4+2]=v.z; al[r][c4+3]=v.w;
        }
        __syncthreads();
        #pragma unroll 4
        for (int e = 0; e < 64; e += 4) {
            const float a0v=al[b][e], a1v=al[b][e+1], a2v=al[b][e+2], a3v=al[b][e+3];
            #pragma unroll
            for (int jj = 0; jj < 4; ++jj) {
                const float4 wq = *(const float4*)&wcat[(size_t)(j0+jj)*1024 + kc*256 + ch*64 + e];
                acc[jj] = fmaf(a0v,wq.x, fmaf(a1v,wq.y, fmaf(a2v,wq.z, fmaf(a3v,wq.w, acc[jj]))));
            }
        }
    }
    #pragma unroll
    for (int jj = 0; jj < 4; ++jj)
        ws[CPART_OFF + ((size_t)kc*NH + j0+jj)*NB + b] = acc[jj];
}

// K5b: sum split-K partials + bias + tanh -> concat_output (bf16 for MFMA k6)
__global__ __launch_bounds__(256) void k5b_concat_fin(
    const float* __restrict__ bcat, float* __restrict__ ws)
{
    const int t = threadIdx.x;
    const int b = t & 63;
    const int j = blockIdx.x * 4 + (t >> 6);
    float v = bcat[j];
    #pragma unroll
    for (int kc = 0; kc < 4; ++kc)
        v += ws[CPART_OFF + ((size_t)kc*NH + j)*NB + b];
    const float e2 = __expf(-2.f * fabsf(v));
    const float th = copysignf((1.f - e2) / (1.f + e2), v);
    unsigned short* ccb = (unsigned short*)(ws + CCB_OFF);
    ccb[b*NH + j] = f2bf(th);
}

// K6: vocab projection via bf16 MFMA, A-matrix (ccb) staged in LDS.
// R8-R12 nulls isolated the real limiter: VMEM line-request count. The per-wave
// ccb A-fragment gathers were 64 instrs x 64 scattered 64B lines = 4096 lines
// (80% of all requests, re-fetched from L2 by every wave of every block).
// Now: stage ccb K-half (32KB) into LDS per block (512 contiguous lines),
// XOR-swizzled (addr ^= (row&7)<<4) so ds_read_b128 A-frags are conflict-free.
// 256-thread blocks x 64 j, grid 786. Accumulation order identical to R7.
__global__ __launch_bounds__(256) void k6_mfma(
    const float* __restrict__ wout, const float* __restrict__ bout,
    const unsigned short* __restrict__ ccb, float* __restrict__ out)
{
    __shared__ unsigned short al[64 * 256];   // 32KB: [64 rows][256 ushort K-half]
    const int t = threadIdx.x;
    const int w = t >> 6;
    const int l = t & 63;
    const int lm = l & 15;
    const int kg = l >> 4;
    const int j = blockIdx.x * 64 + w * 16 + lm;
    const int jc = j < NV ? j : NV - 1;
    const float* wrow = wout + (size_t)jc * NH + kg * 8;
    f32x4 acc0 = {0.f,0.f,0.f,0.f};
    f32x4 acc1 = {0.f,0.f,0.f,0.f};
    f32x4 acc2 = {0.f,0.f,0.f,0.f};
    f32x4 acc3 = {0.f,0.f,0.f,0.f};
    char* alb = (char*)al;
    #pragma unroll
    for (int ph = 0; ph < 2; ++ph) {
        if (ph) __syncthreads();          // all phase-0 reads done before overwrite
        // stage rows 0..63 x K-half ph: 2048 chunks of 16B, coalesced
        #pragma unroll
        for (int i = 0; i < 8; ++i) {
            const int c = i * 256 + t;
            const int row = c >> 5;               // 32 chunks per row
            const int cu = (c & 31) * 8;          // ushort col within half
            const uint4 v = *(const uint4*)&ccb[row * NH + ph * 256 + cu];
            const int dst = (row * 512 + cu * 2) ^ ((row & 7) << 4);
            *(uint4*)(alb + dst) = v;
        }
        __syncthreads();
        #pragma unroll
        for (int k8 = 0; k8 < 8; ++k8) {
            const int ks = ph * 8 + k8;
            const float4 w0 = *(const float4*)(wrow + ks * 32);
            const float4 w1 = *(const float4*)(wrow + ks * 32 + 4);
            bf16x8 bf;
            bf[0] = (short)f2bf(w0.x); bf[1] = (short)f2bf(w0.y);
            bf[2] = (short)f2bf(w0.z); bf[3] = (short)f2bf(w0.w);
            bf[4] = (short)f2bf(w1.x); bf[5] = (short)f2bf(w1.y);
            bf[6] = (short)f2bf(w1.z); bf[7] = (short)f2bf(w1.w);
            const int kb = k8 * 64 + kg * 16;     // byte offset within half-row
            const int r0 = lm,      s0 = (r0 * 512 + kb) ^ ((r0 & 7) << 4);
            const int r1 = 16 + lm, s1 = (r1 * 512 + kb) ^ ((r1 & 7) << 4);
            const int r2 = 32 + lm, s2 = (r2 * 512 + kb) ^ ((r2 & 7) << 4);
            const int r3 = 48 + lm, s3 = (r3 * 512 + kb) ^ ((r3 & 7) << 4);
            const bf16x8 a0 = *(const bf16x8*)(alb + s0);
            const bf16x8 a1 = *(const bf16x8*)(alb + s1);
            const bf16x8 a2 = *(const bf16x8*)(alb + s2);
            const bf16x8 a3 = *(const bf16x8*)(alb + s3);
            acc0 = __builtin_amdgcn_mfma_f32_16x16x32_bf16(a0, bf, acc0, 0, 0, 0);
            acc1 = __builtin_amdgcn_mfma_f32_16x16x32_bf16(a1, bf, acc1, 0, 0, 0);
            acc2 = __builtin_amdgcn_mfma_f32_16x16x32_bf16(a2, bf, acc2, 0, 0, 0);
            acc3 = __builtin_amdgcn_mfma_f32_16x16x32_bf16(a3, bf, acc3, 0, 0, 0);
        }
    }
    if (j < NV) {
        const float bj = bout[jc];
        #pragma unroll
        for (int r = 0; r < 4; ++r) {
            out[(size_t)(0*16 + kg*4 + r) * NV + j] = acc0[r] + bj;
            out[(size_t)(1*16 + kg*4 + r) * NV + j] = acc1[r] + bj;
            out[(size_t)(2*16 + kg*4 + r) * NV + j] = acc2[r] + bj;
            out[(size_t)(3*16 + kg*4 + r) * NV + j] = acc3[r] + bj;
        }
    }
}

extern "C" void kernel_launch(void* const* d_in, const int* in_sizes, int n_in,
                              void* d_out, int out_size, void* d_ws, size_t ws_size,
                              hipStream_t stream) {
    (void)in_sizes; (void)n_in; (void)out_size; (void)ws_size;
    const int*   seq  = (const int*)  d_in[0];
    const float* lh   = (const float*)d_in[1];
    const float* enc  = (const float*)d_in[2];
    const float* emb  = (const float*)d_in[3];
    const float* wih  = (const float*)d_in[4];
    const float* whh  = (const float*)d_in[5];
    const float* bih  = (const float*)d_in[6];
    const float* bhh  = (const float*)d_in[7];
    const float* wcat = (const float*)d_in[8];
    const float* bcat = (const float*)d_in[9];
    const float* wout = (const float*)d_in[10];
    const float* bout = (const float*)d_in[11];
    float* out = (float*)d_out;
    float* ws  = (float*)d_ws;

    k1_gru_gemm <<<dim3(96, KSL), 256, 0, stream>>>(seq, lh, emb, wih, whh, ws);
    k2_gates    <<<128, 256, 0, stream>>>(lh, bih, bhh, ws, out);
    k3_attn     <<<2048, 256, 0, stream>>>(enc, ws);
    k4_combine  <<<dim3(64, 4), 256, 0, stream>>>(ws, out);
    k5_concat_gemm<<<dim3(32, 4), 256, 0, stream>>>(wcat, ws);
    k5b_concat_fin<<<128, 256, 0, stream>>>(bcat, ws);
    k6_mfma     <<<786, 256, 0, stream>>>(wout, bout,
                     (const unsigned short*)(ws + CCB_OFF), out);
}